// Round 4
// baseline (3639.639 us; speedup 1.0000x reference)
//
#include <hip/hip_runtime.h>
#include <hip/hip_cooperative_groups.h>
#include <cstddef>

namespace cg = cooperative_groups;

#define NT   8
#define NN   100000
#define NE   1600000
#define DIN  64
#define DH   64
#define DE   16
#define FLAT 4096
#define BN   1024

__device__ __forceinline__ void atomAdd(float* p, float v) { unsafeAtomicAdd(p, v); }

__device__ __forceinline__ void fma4(float4& a, float s, const float4& w) {
  a.x = fmaf(s, w.x, a.x); a.y = fmaf(s, w.y, a.y);
  a.z = fmaf(s, w.z, a.z); a.w = fmaf(s, w.w, a.w);
}

// ---------------- init: zero cnt ---------------------------------------------------
__global__ void k_init(int* __restrict__ cnt) {
  int i = blockIdx.x * blockDim.x + threadIdx.x;
  for (int n = i; n < NN; n += gridDim.x * blockDim.x) cnt[n] = 0;
}

// ---------------- persistent cooperative ODE: all 7 RK4 steps in one launch --------
// 256 blocks (1/CU). Block b owns w1 cols [b*4,b*4+4) and w2 cols [b*16,b*16+16),
// staged to LDS ONCE (128 KB). Step base w and k1..k4 for owned indices stay in
// LDS across the whole chain. Per eval: A = win@w1 (per-wave dot) -> acc1 global
// (4 floats/block) -> grid.sync -> B = tanh(acc1+b1)@w2 slice -> RK4 update of
// owned 16 w-elements -> win_g global -> grid.sync. 56 grid syncs total replace
// 57 kernel launches.
__global__ __launch_bounds__(256) void k_ode(
    const float* __restrict__ init_w, const float* __restrict__ w1g,
    const float* __restrict__ b1g, const float* __restrict__ w2g,
    const float* __restrict__ b2g, float* __restrict__ win_g,
    float* __restrict__ accg, float* __restrict__ WT) {
  __shared__ float w1s[4][FLAT];     // 64 KB: w1s[jj][i] = w1[i][b*4+jj]
  __shared__ float w2s[BN][16];      // 64 KB: w2s[j][ii] = w2[j][b*16+ii]
  __shared__ float win_l[FLAT];      // 16 KB
  __shared__ float tl[BN];           // 4 KB
  __shared__ float b1s[BN];          // 4 KB
  __shared__ float red[256];         // 1 KB
  __shared__ float wloc[16], b2loc[16], karr[4][16];
  cg::grid_group grid = cg::this_grid();
  const int t = threadIdx.x, b = blockIdx.x;
  const int lane = t & 63, wv = t >> 6;

  // ---- one-time weight staging ----
  for (int i = t; i < FLAT; i += 256) {
    float4 v = *(const float4*)&w1g[(size_t)i * BN + b * 4];
    w1s[0][i] = v.x; w1s[1][i] = v.y; w1s[2][i] = v.z; w1s[3][i] = v.w;
  }
  for (int q = t; q < BN * 4; q += 256) {
    int j = q >> 2, qq = (q & 3) * 4;
    float4 v = *(const float4*)&w2g[(size_t)j * FLAT + b * 16 + qq];
    w2s[j][qq] = v.x; w2s[j][qq + 1] = v.y; w2s[j][qq + 2] = v.z; w2s[j][qq + 3] = v.w;
  }
  for (int q = t; q < BN; q += 256) b1s[q] = b1g[q];
  if (t < 16) { wloc[t] = init_w[b * 16 + t]; b2loc[t] = b2g[b * 16 + t]; }
  __syncthreads();

  const float hh = 1.0f / 7.0f;
  for (int s = 0; s < 7; ++s) {
    for (int c = 0; c < 4; ++c) {
      // ---- stage win (eval point) ----
      const float* wsrc = (s == 0 && c == 0) ? init_w : win_g;
      for (int q = t; q < BN; q += 256)
        *(float4*)&win_l[q * 4] = *(const float4*)&wsrc[q * 4];
      __syncthreads();
      // ---- phase A: wave wv computes acc1[b*4+wv] ----
      float acc = 0.f;
#pragma unroll 8
      for (int it = 0; it < 64; ++it) {
        int i = it * 64 + lane;
        acc = fmaf(win_l[i], w1s[wv][i], acc);
      }
      acc += __shfl_xor(acc, 1);
      acc += __shfl_xor(acc, 2);
      acc += __shfl_xor(acc, 4);
      acc += __shfl_xor(acc, 8);
      acc += __shfl_xor(acc, 16);
      acc += __shfl_xor(acc, 32);
      if (lane == 0) accg[b * 4 + wv] = acc;
      __threadfence();
      grid.sync();
      // ---- phase B: tl = tanh(acc1+b1), y2[ii] for owned 16 i's ----
      for (int q = t; q < BN; q += 256) tl[q] = tanhf(accg[q] + b1s[q]);
      __syncthreads();
      const int ii = t & 15, jg = t >> 4;
      float part = 0.f;
#pragma unroll 8
      for (int jt = 0; jt < 64; ++jt) {
        int j = jg * 64 + jt;
        part = fmaf(tl[j], w2s[j][ii], part);
      }
      red[t] = part;
      __syncthreads();
      if (t < 16) {
        float y = b2loc[t];
#pragma unroll
        for (int k = 0; k < 16; ++k) y += red[k * 16 + t];
        karr[c][t] = y;
        float wn;
        if (c == 0)      wn = wloc[t] + hh * y * (1.f / 3.f);
        else if (c == 1) wn = wloc[t] + hh * (y - karr[0][t] * (1.f / 3.f));
        else if (c == 2) wn = wloc[t] + hh * (karr[0][t] - karr[1][t] + y);
        else {
          wn = wloc[t] + hh * 0.125f * (karr[0][t] + 3.f * (karr[1][t] + karr[2][t]) + y);
          wloc[t] = wn;                      // new step base
        }
        win_g[b * 16 + t] = wn;              // next eval point
      }
      __threadfence();
      grid.sync();
    }
  }
  if (t < 16) WT[b * 16 + t] = wloc[t];
}

// ---------------- CSR build: histogram by col --------------------------------------
__global__ void k_hist(const int* __restrict__ ei, int* __restrict__ cnt) {
  int e = blockIdx.x * blockDim.x + threadIdx.x;
  if (e < NE) atomicAdd(&cnt[ei[NE + e]], 1);
}

// ---------------- scan step 1: per-block exclusive scan of cnt ---------------------
__global__ __launch_bounds__(256) void k_scan1(const int* __restrict__ cnt,
                                               int* __restrict__ offs,
                                               int* __restrict__ bsum) {
  __shared__ int s[256];
  const int t = threadIdx.x;
  const int i = blockIdx.x * 256 + t;
  int v = (i < NN) ? cnt[i] : 0;
  s[t] = v;
  __syncthreads();
  for (int off = 1; off < 256; off <<= 1) {
    int x = (t >= off) ? s[t - off] : 0;
    __syncthreads();
    s[t] += x;
    __syncthreads();
  }
  if (i < NN) offs[i] = s[t] - v;          // exclusive
  if (t == 255) bsum[blockIdx.x] = s[255];
}

// ---------------- scan step 2: scan of block sums (single block) -------------------
__global__ __launch_bounds__(512) void k_scan2(int* __restrict__ bsum,
                                               int* __restrict__ bofs, int nblk) {
  __shared__ int s[512];
  const int t = threadIdx.x;
  int v = (t < nblk) ? bsum[t] : 0;
  s[t] = v;
  __syncthreads();
  for (int off = 1; off < 512; off <<= 1) {
    int x = (t >= off) ? s[t - off] : 0;
    __syncthreads();
    s[t] += x;
    __syncthreads();
  }
  if (t < nblk) bofs[t] = s[t] - v;        // exclusive
}

// ---------------- scan step 3: add block offsets, init cursors, dis ----------------
__global__ __launch_bounds__(256) void k_scan3(const int* __restrict__ cnt,
                                               int* __restrict__ offs,
                                               const int* __restrict__ bofs,
                                               int* __restrict__ cur,
                                               float* __restrict__ dis) {
  const int i = blockIdx.x * 256 + threadIdx.x;
  if (i < NN) {
    int o = offs[i] + bofs[i >> 8];
    offs[i] = o;
    cur[i] = o;
    dis[i] = rsqrtf((float)(cnt[i] + 1));  // +1 self-loop, deg >= 1 always
  }
  if (i == 0) offs[NN] = NE;
}

// ---------------- CSR fill: csr[pos] = (row, edge_id), bucketed by col -------------
__global__ void k_fill(const int* __restrict__ ei, int* __restrict__ cur,
                       int2* __restrict__ csr) {
  int e = blockIdx.x * blockDim.x + threadIdx.x;
  if (e < NE) {
    int row = ei[e], col = ei[NE + e];
    int pos = atomicAdd(&cur[col], 1);
    csr[pos] = make_int2(row, e);
  }
}

// ---------------- xw = x_last @ W_T : 16 lanes/node, 4 nodes/thread-group ----------
__global__ __launch_bounds__(256) void k_xw(
    const float* __restrict__ x_last, const float* __restrict__ WT,
    float* __restrict__ xw) {
  __shared__ float wt[FLAT];
  for (int i = threadIdx.x; i < FLAT; i += 256) wt[i] = WT[i];
  __syncthreads();
  const int lane = threadIdx.x & 15;
  const int grp = threadIdx.x >> 4;
  const int n0 = blockIdx.x * 64 + grp * 4;
  if (n0 >= NN) return;
  const int nvalid = (NN - n0 < 4) ? (NN - n0) : 4;
  const float4* xp[4];
#pragma unroll
  for (int m = 0; m < 4; ++m) {
    int n = (m < nvalid) ? (n0 + m) : n0;
    xp[m] = (const float4*)(x_last + (size_t)n * 64);
  }
  float4 acc[4];
#pragma unroll
  for (int m = 0; m < 4; ++m) acc[m] = make_float4(0.f, 0.f, 0.f, 0.f);
#pragma unroll
  for (int q = 0; q < 16; ++q) {
    const float* wr = &wt[(q * 4) * 64 + lane * 4];
    float4 w0 = *(const float4*)&wr[0];
    float4 w1 = *(const float4*)&wr[64];
    float4 w2 = *(const float4*)&wr[128];
    float4 w3 = *(const float4*)&wr[192];
#pragma unroll
    for (int m = 0; m < 4; ++m) {
      float4 x4 = xp[m][q];          // same addr across 16 lanes -> broadcast
      fma4(acc[m], x4.x, w0); fma4(acc[m], x4.y, w1);
      fma4(acc[m], x4.z, w2); fma4(acc[m], x4.w, w3);
    }
  }
  for (int m = 0; m < nvalid; ++m)
    *(float4*)&xw[(size_t)(n0 + m) * 64 + lane * 4] = acc[m];
}

// ---------------- pass 1: h[col] = relu(sum_e norm*xw[row] + d^2*xw[col]) ----------
// one 64-lane wave per node, lane = feature index; 4-wide unrolled gather walk.
__global__ __launch_bounds__(256) void k_gh(
    const int* __restrict__ offs, const int2* __restrict__ csr,
    const float* __restrict__ dis, const float* __restrict__ xw,
    float* __restrict__ h) {
  const int node = blockIdx.x * 4 + (threadIdx.x >> 6);
  const int lane = threadIdx.x & 63;
  if (node >= NN) return;
  const int off0 = offs[node], off1 = offs[node + 1];
  const float d = dis[node];
  float acc = d * d * xw[(size_t)node * 64 + lane];
  int e = off0;
  for (; e + 3 < off1; e += 4) {
    int2 c0 = csr[e], c1 = csr[e + 1], c2 = csr[e + 2], c3 = csr[e + 3];
    float x0 = xw[(size_t)c0.x * 64 + lane];
    float x1 = xw[(size_t)c1.x * 64 + lane];
    float x2 = xw[(size_t)c2.x * 64 + lane];
    float x3 = xw[(size_t)c3.x * 64 + lane];
    float n0 = d * dis[c0.x], n1 = d * dis[c1.x];
    float n2 = d * dis[c2.x], n3 = d * dis[c3.x];
    acc = fmaf(n0, x0, acc);
    acc = fmaf(n1, x1, acc);
    acc = fmaf(n2, x2, acc);
    acc = fmaf(n3, x3, acc);
  }
  for (; e < off1; ++e) {
    int2 c0 = csr[e];
    acc = fmaf(d * dis[c0.x], xw[(size_t)c0.x * 64 + lane], acc);
  }
  h[(size_t)node * 64 + lane] = fmaxf(acc, 0.f);
}

// ---------------- finalize: A = h@W1a (in place over h), B = h@W1b + b1 ------------
__global__ __launch_bounds__(256) void k_finalize(
    const float* __restrict__ mlp_w1, const float* __restrict__ mlp_b1,
    float* __restrict__ hA, float* __restrict__ Bb) {
  __shared__ float wa[FLAT];
  __shared__ float wb[FLAT];
  for (int i = threadIdx.x; i < FLAT; i += 256) {
    wa[i] = mlp_w1[i];
    wb[i] = mlp_w1[FLAT + i];
  }
  __syncthreads();
  const int lane = threadIdx.x & 15;
  const int grp = threadIdx.x >> 4;
  const int n0 = blockIdx.x * 64 + grp * 4;
  if (n0 >= NN) return;
  const int nvalid = (NN - n0 < 4) ? (NN - n0) : 4;
  const float4 b1v = ((const float4*)mlp_b1)[lane];   // fold b1 into B once
  const float4* hp[4];
#pragma unroll
  for (int m = 0; m < 4; ++m) {
    int n = (m < nvalid) ? (n0 + m) : n0;
    hp[m] = (const float4*)(hA + (size_t)n * 64);
  }
  float4 aA[4], aB[4];
#pragma unroll
  for (int m = 0; m < 4; ++m) { aA[m] = make_float4(0,0,0,0); aB[m] = make_float4(0,0,0,0); }
#pragma unroll
  for (int q = 0; q < 16; ++q) {
    const float* war = &wa[(q * 4) * 64 + lane * 4];
    const float* wbr = &wb[(q * 4) * 64 + lane * 4];
    float4 wa0 = *(const float4*)&war[0];
    float4 wa1 = *(const float4*)&war[64];
    float4 wa2 = *(const float4*)&war[128];
    float4 wa3 = *(const float4*)&war[192];
    float4 wb0 = *(const float4*)&wbr[0];
    float4 wb1 = *(const float4*)&wbr[64];
    float4 wb2 = *(const float4*)&wbr[128];
    float4 wb3 = *(const float4*)&wbr[192];
#pragma unroll
    for (int m = 0; m < 4; ++m) {
      float4 h4 = hp[m][q];
      fma4(aA[m], h4.x, wa0); fma4(aA[m], h4.y, wa1); fma4(aA[m], h4.z, wa2); fma4(aA[m], h4.w, wa3);
      fma4(aB[m], h4.x, wb0); fma4(aB[m], h4.y, wb1); fma4(aB[m], h4.z, wb2); fma4(aB[m], h4.w, wb3);
    }
  }
  for (int m = 0; m < nvalid; ++m) {
    *(float4*)&hA[(size_t)(n0 + m) * 64 + lane * 4] = aA[m];   // wave-lockstep: reads done
    float4 bo = aB[m];
    bo.x += b1v.x; bo.y += b1v.y; bo.z += b1v.z; bo.w += b1v.w;
    *(float4*)&Bb[(size_t)(n0 + m) * 64 + lane * 4] = bo;
  }
}

// ---------------- pass 2: edge MLP, edge-parallel, 8 edges per wave ----------------
// All 16 A/B gathers (the random long-latency loads; only 16 VGPRs) are issued
// before ANY compute. eattr/out stream sequentially. E-values consumed in two
// 4-edge halves. readfirstlane makes e0 wave-uniform -> scalar loads for
// rows/cols/eattr bases (VGPR=20 last round confirmed).
__global__ __launch_bounds__(256) void k_emlp(
    const int* __restrict__ ei, const float* __restrict__ A,
    const float* __restrict__ Bb, const float* __restrict__ eattr,
    const float* __restrict__ mlp_w1, const float* __restrict__ mlp_w2,
    const float* __restrict__ mlp_b2, float* __restrict__ out) {
  const int lane = threadIdx.x & 63;
  const int e0 = __builtin_amdgcn_readfirstlane((blockIdx.x * 4 + (threadIdx.x >> 6)) * 8);
  if (e0 >= NE) return;
  float wc[16];
#pragma unroll
  for (int f = 0; f < 16; ++f) wc[f] = mlp_w1[(size_t)(128 + f) * 64 + lane];
  const float w2l = mlp_w2[lane];
  const float b2v = mlp_b2[0];
  const int4 r01 = *(const int4*)&ei[e0];            // uniform -> s_load
  const int4 r23 = *(const int4*)&ei[e0 + 4];
  const int4 c01 = *(const int4*)&ei[NE + e0];
  const int4 c23 = *(const int4*)&ei[NE + e0 + 4];
  // ---- all 16 random gathers in flight before any compute (16 VGPRs) ----
  const float av0 = A[(size_t)r01.x * 64 + lane], bv0 = Bb[(size_t)c01.x * 64 + lane];
  const float av1 = A[(size_t)r01.y * 64 + lane], bv1 = Bb[(size_t)c01.y * 64 + lane];
  const float av2 = A[(size_t)r01.z * 64 + lane], bv2 = Bb[(size_t)c01.z * 64 + lane];
  const float av3 = A[(size_t)r01.w * 64 + lane], bv3 = Bb[(size_t)c01.w * 64 + lane];
  const float av4 = A[(size_t)r23.x * 64 + lane], bv4 = Bb[(size_t)c23.x * 64 + lane];
  const float av5 = A[(size_t)r23.y * 64 + lane], bv5 = Bb[(size_t)c23.y * 64 + lane];
  const float av6 = A[(size_t)r23.z * 64 + lane], bv6 = Bb[(size_t)c23.z * 64 + lane];
  const float av7 = A[(size_t)r23.w * 64 + lane], bv7 = Bb[(size_t)c23.w * 64 + lane];
  const float4* ep = (const float4*)(eattr + (size_t)e0 * 16);  // uniform base

#define EDOT(acc, Ea, Eb, Ec, Ed)                                    \
  acc = fmaf(Ea.x, wc[0], acc);  acc = fmaf(Ea.y, wc[1], acc);       \
  acc = fmaf(Ea.z, wc[2], acc);  acc = fmaf(Ea.w, wc[3], acc);       \
  acc = fmaf(Eb.x, wc[4], acc);  acc = fmaf(Eb.y, wc[5], acc);       \
  acc = fmaf(Eb.z, wc[6], acc);  acc = fmaf(Eb.w, wc[7], acc);       \
  acc = fmaf(Ec.x, wc[8], acc);  acc = fmaf(Ec.y, wc[9], acc);       \
  acc = fmaf(Ec.z, wc[10], acc); acc = fmaf(Ec.w, wc[11], acc);      \
  acc = fmaf(Ed.x, wc[12], acc); acc = fmaf(Ed.y, wc[13], acc);      \
  acc = fmaf(Ed.z, wc[14], acc); acc = fmaf(Ed.w, wc[15], acc)

  float p0, p1, p2, p3, p4, p5, p6, p7;
  {  // half 0: edges 0-3
    float4 E00 = ep[0],  E01 = ep[1],  E02 = ep[2],  E03 = ep[3];
    float4 E10 = ep[4],  E11 = ep[5],  E12 = ep[6],  E13 = ep[7];
    float4 E20 = ep[8],  E21 = ep[9],  E22 = ep[10], E23 = ep[11];
    float4 E30 = ep[12], E31 = ep[13], E32 = ep[14], E33 = ep[15];
    p0 = av0 + bv0; EDOT(p0, E00, E01, E02, E03); p0 = fmaxf(p0, 0.f) * w2l;
    p1 = av1 + bv1; EDOT(p1, E10, E11, E12, E13); p1 = fmaxf(p1, 0.f) * w2l;
    p2 = av2 + bv2; EDOT(p2, E20, E21, E22, E23); p2 = fmaxf(p2, 0.f) * w2l;
    p3 = av3 + bv3; EDOT(p3, E30, E31, E32, E33); p3 = fmaxf(p3, 0.f) * w2l;
  }
  {  // half 1: edges 4-7
    float4 E00 = ep[16], E01 = ep[17], E02 = ep[18], E03 = ep[19];
    float4 E10 = ep[20], E11 = ep[21], E12 = ep[22], E13 = ep[23];
    float4 E20 = ep[24], E21 = ep[25], E22 = ep[26], E23 = ep[27];
    float4 E30 = ep[28], E31 = ep[29], E32 = ep[30], E33 = ep[31];
    p4 = av4 + bv4; EDOT(p4, E00, E01, E02, E03); p4 = fmaxf(p4, 0.f) * w2l;
    p5 = av5 + bv5; EDOT(p5, E10, E11, E12, E13); p5 = fmaxf(p5, 0.f) * w2l;
    p6 = av6 + bv6; EDOT(p6, E20, E21, E22, E23); p6 = fmaxf(p6, 0.f) * w2l;
    p7 = av7 + bv7; EDOT(p7, E30, E31, E32, E33); p7 = fmaxf(p7, 0.f) * w2l;
  }
#undef EDOT

  // packed butterfly: 8 reductions in 17 shuffles; lane l (<8) ends with edge l sum
  p0 += __shfl_xor(p0, 1); p1 += __shfl_xor(p1, 1);
  p2 += __shfl_xor(p2, 1); p3 += __shfl_xor(p3, 1);
  p4 += __shfl_xor(p4, 1); p5 += __shfl_xor(p5, 1);
  p6 += __shfl_xor(p6, 1); p7 += __shfl_xor(p7, 1);
  float u0 = (lane & 1) ? p1 : p0;
  float u1 = (lane & 1) ? p3 : p2;
  float u2 = (lane & 1) ? p5 : p4;
  float u3 = (lane & 1) ? p7 : p6;
  u0 += __shfl_xor(u0, 2); u1 += __shfl_xor(u1, 2);
  u2 += __shfl_xor(u2, 2); u3 += __shfl_xor(u3, 2);
  float v0 = (lane & 2) ? u1 : u0;
  float v1 = (lane & 2) ? u3 : u2;
  v0 += __shfl_xor(v0, 4); v1 += __shfl_xor(v1, 4);
  float s = (lane & 4) ? v1 : v0;
  s += __shfl_xor(s, 8);
  s += __shfl_xor(s, 16);
  s += __shfl_xor(s, 32);
  if (lane < 8) out[e0 + lane] = s + b2v;        // sequential 32B store per wave
}

extern "C" void kernel_launch(void* const* d_in, const int* in_sizes, int n_in,
                              void* d_out, int out_size, void* d_ws, size_t ws_size,
                              hipStream_t stream) {
  (void)in_sizes; (void)n_in; (void)out_size; (void)ws_size;
  const float* x_seq  = (const float*)d_in[0];
  const float* eattr  = (const float*)d_in[1];
  const float* init_w = (const float*)d_in[2];
  const float* ode_w1 = (const float*)d_in[3];
  const float* ode_b1 = (const float*)d_in[4];
  const float* ode_w2 = (const float*)d_in[5];
  const float* ode_b2 = (const float*)d_in[6];
  const float* mlp_w1 = (const float*)d_in[7];
  const float* mlp_b1 = (const float*)d_in[8];
  const float* mlp_w2 = (const float*)d_in[9];
  const float* mlp_b2 = (const float*)d_in[10];
  const int*   eidx   = (const int*)d_in[11];
  float* out = (float*)d_out;

  float* ws    = (float*)d_ws;
  float* win_g = ws;                         // [FLAT]   (next-eval w argument)
  float* accg  = ws + 8 * FLAT;              // [BN]
  float* WT    = ws + 10 * FLAT;             // [FLAT]
  float* dis   = ws + 49152;                 // [NN]
  int*   cnt   = (int*)(ws + 149152);        // [NN]
  int*   offs  = (int*)(ws + 249152);        // [NN+1]
  int*   bsum  = (int*)(ws + 349184);        // [512]
  int*   bofs  = (int*)(ws + 349696);        // [512]
  int*   cur   = (int*)(ws + 350208);        // [NN]
  int2*  csr   = (int2*)(ws + 450560);       // [NE] (row, eid)
  float* xw    = ws + 450560 + 2 * (size_t)NE;  // [NN*64]; becomes B+b1 after finalize
  float* hA    = xw + (size_t)NN * 64;       // [NN*64]: h -> A in place
  // total ~66 MB of ws

  const int nblk_n = (NN + 255) / 256;       // 391

  k_init<<<128, 256, 0, stream>>>(cnt);
  k_hist<<<(NE + 255) / 256, 256, 0, stream>>>(eidx, cnt);
  k_scan1<<<nblk_n, 256, 0, stream>>>(cnt, offs, bsum);
  k_scan2<<<1, 512, 0, stream>>>(bsum, bofs, nblk_n);
  k_scan3<<<nblk_n, 256, 0, stream>>>(cnt, offs, bofs, cur, dis);
  k_fill<<<(NE + 255) / 256, 256, 0, stream>>>(eidx, cur, csr);

  // ---- entire 7-step RK4 weight-ODE in one cooperative launch ----
  {
    void* kargs[] = {(void*)&init_w, (void*)&ode_w1, (void*)&ode_b1,
                     (void*)&ode_w2, (void*)&ode_b2, (void*)&win_g,
                     (void*)&accg, (void*)&WT};
    hipLaunchCooperativeKernel((void*)k_ode, dim3(256), dim3(256), kargs, 0, stream);
  }

  k_xw<<<(NN + 63) / 64, 256, 0, stream>>>(x_seq + (size_t)(NT - 1) * NN * DIN, WT, xw);
  k_gh<<<(NN + 3) / 4, 256, 0, stream>>>(offs, csr, dis, xw, hA);
  k_finalize<<<(NN + 63) / 64, 256, 0, stream>>>(mlp_w1, mlp_b1, hA, xw); // A in hA, B+b1 in xw
  k_emlp<<<NE / 32, 256, 0, stream>>>(eidx, hA, xw, eattr,
                                      mlp_w1, mlp_w2, mlp_b2, out);
}